// Round 17
// baseline (37.417 us; speedup 1.0000x reference)
//
#include <hip/hip_runtime.h>

namespace {
constexpr int kM = 4, kJ = 2, kI = 3, kL = 2, kW = 9;
constexpr float kInvLn2 = 1.4426950408889634f;

__device__ __forceinline__ float fexp2(float x) { return __builtin_amdgcn_exp2f(x); }

// 2 elements/thread, all-scalar body. sdp: 4 records x 20 floats:
//   [0]An0 [1]An1 [2]B0n0 [3]B0n1 [4]B1n0 [5]B1n1 [6]w0n0 [7]w0n1
//   [8]w1n0 [9]w1n1 [10]C000 [11]C001 [12]C010 [13]C011 [14]C100 [15]C101
//   [16]C110 [17]C111 [18]D0 [19]D1
// msN_j = An_j + sx*(B0n_j + w0n_j*sx) + sy*(B1n_j + w1n_j*sy) = -ms/ln2 <= 0
__global__ __launch_bounds__(256) void algelogic_pair(
    const float* __restrict__ state,
    const float* __restrict__ constants,
    const float* __restrict__ gammas,
    const float* __restrict__ W_body,
    const float* __restrict__ b_body,
    const float* __restrict__ W_head,
    const float* __restrict__ b_head,
    float* __restrict__ out) {
  __shared__ float sdp[80];
  const int t = threadIdx.x;
  const size_t pi = (size_t)blockIdx.x * 256 + t;   // pair index

  // ---- pair loads first (9x dwordx4, 16B-aligned: pair base = pi*144B) ----
  const float4* sq = reinterpret_cast<const float4*>(state) + pi * 9;
  float4 sF[9];
#pragma unroll
  for (int k = 0; k < 9; ++k) sF[k] = sq[k];

  // ---- param fold (R10 pattern): wave0 lanes 0-7 coeffs+C; wave1 D ----
  if (t < 8) {
    const int mj = t, m = t >> 1, j = t & 1;
    const float g0 = fminf(fmaxf(gammas[mj * kL + 0], 0.f), 1.f);
    const float g1 = fminf(fmaxf(gammas[mj * kL + 1], 0.f), 1.f);
    const float w0 = 1.f - g0, w1 = 1.f - g1;
    const float c0 = constants[mj * kL + 0], c1 = constants[mj * kL + 1];
    const float gavg = 0.5f * (g0 + g1);
    float* base = sdp + m * 20;
    base[0 + j] = -(w0 * c0 * c0 + w1 * c1 * c1) * kInvLn2;  // An
    base[2 + j] = 2.f * w0 * c0 * kInvLn2;                   // B0n
    base[4 + j] = 2.f * w1 * c1 * kInvLn2;                   // B1n
    base[6 + j] = -w0 * kInvLn2;                             // w0n
    base[8 + j] = -w1 * kInvLn2;                             // w1n
#pragma unroll
    for (int l = 0; l < kL; ++l)
#pragma unroll
      for (int lp = 0; lp < kL; ++lp) {
        float acc = 0.f;
#pragma unroll
        for (int i = 0; i < kI; ++i)
          acc += W_head[(m * kL + l) * kI + i] * W_body[(mj * kI + i) * kL + lp];
        base[10 + (l * 2 + lp) * 2 + j] = gavg * acc;        // C[l][lp], j
      }
  } else if (t >= 64 && t < 68) {
    const int m = t - 64;
#pragma unroll
    for (int l = 0; l < kL; ++l) {
      float d = b_head[m * kL + l];
#pragma unroll
      for (int j = 0; j < kJ; ++j) {
        const int mj = m * kJ + j;
        const float g0 = fminf(fmaxf(gammas[mj * kL + 0], 0.f), 1.f);
        const float g1 = fminf(fmaxf(gammas[mj * kL + 1], 0.f), 1.f);
        const float gavg = 0.5f * (g0 + g1);
        float acc = 0.f;
#pragma unroll
        for (int i = 0; i < kI; ++i)
          acc += W_head[(m * kL + l) * kI + i] * b_body[mj * kI + i];
        d += gavg * acc;
      }
      sdp[m * 20 + 18 + l] = d;
    }
  }
  __syncthreads();

  float Cs[2] = {0.f, 0.f}, X0[2] = {0.f, 0.f}, X1[2] = {0.f, 0.f},
        K[2] = {0.f, 0.f};

#pragma unroll 1   // one m live at a time; params shared by both elements
  for (int m = 0; m < kM; ++m) {
    const float4* P4 = reinterpret_cast<const float4*>(sdp + m * 20);
    const float4 f0 = P4[0], f1 = P4[1], f2 = P4[2], f3 = P4[3], f4 = P4[4];

#pragma unroll
    for (int elem = 0; elem < 2; ++elem) {
      float p0 = 1e-35f, p1 = 1e-35f;    // psum guards
      float a0 = 0.f, a1 = 0.f;          // e*sx
      float b0 = 0.f, b1 = 0.f;          // e*sy
      float q0 = 0.f, q1 = 0.f;          // e*msN
#pragma unroll
      for (int w = 0; w < kW; ++w) {
        const int g = elem * 9 + w;      // compile-time under full unroll
        const float4 f = sF[g >> 1];
        const float sx = (g & 1) ? f.z : f.x;
        const float sy = (g & 1) ? f.w : f.y;
        // premise j0
        float u = fmaf(f1.z, sx, f0.z);
        float mN0 = fmaf(u, sx, f0.x);
        float v = fmaf(f2.x, sy, f1.x);
        mN0 = fmaf(v, sy, mN0);
        const float e0 = fexp2(mN0);
        p0 += e0;
        a0 = fmaf(e0, sx, a0);
        b0 = fmaf(e0, sy, b0);
        q0 = fmaf(e0, mN0, q0);
        // premise j1
        float u1 = fmaf(f1.w, sx, f0.w);
        float mN1 = fmaf(u1, sx, f0.y);
        float v1 = fmaf(f2.y, sy, f1.y);
        mN1 = fmaf(v1, sy, mN1);
        const float e1 = fexp2(mN1);
        p1 += e1;
        a1 = fmaf(e1, sx, a1);
        b1 = fmaf(e1, sy, b1);
        q1 = fmaf(e1, mN1, q1);
      }

      const float i0 = __builtin_amdgcn_rcpf(p0);
      const float i1 = __builtin_amdgcn_rcpf(p1);
      const float bb00 = a0 * i0, bb10 = b0 * i0;
      const float bb01 = a1 * i1, bb11 = b1 * i1;
      const float mq2 = fmaf(q0, i0, q1 * i1);
      const float conf = fexp2(mq2);             // exp(-mq)

      float r0 = fmaf(f2.z, bb00, f4.z);
      r0 = fmaf(f3.x, bb10, r0);
      r0 = fmaf(f2.w, bb01, r0);
      r0 = fmaf(f3.y, bb11, r0);
      float r1 = fmaf(f3.z, bb00, f4.w);
      r1 = fmaf(f4.x, bb10, r1);
      r1 = fmaf(f3.w, bb01, r1);
      r1 = fmaf(f4.y, bb11, r1);

      Cs[elem] += conf;
      X0[elem] = fmaf(conf, r0, X0[elem]);
      X1[elem] = fmaf(conf, r1, X1[elem]);
      K[elem] = fmaf(conf, fmaf(r0, r0, r1 * r1), K[elem]);
    }
  }

  // ---- epilogue: 18 outputs, float2-vectorized where 8B-aligned ----
  float* orow = out + pi * (2 * kW);
#pragma unroll
  for (int elem = 0; elem < 2; ++elem) {
    const float X02 = 2.f * X0[elem], X12 = 2.f * X1[elem];
    const float Csl = Cs[elem], Kl = K[elem];
    float o[kW];
#pragma unroll
    for (int w = 0; w < kW; ++w) {
      const int g = elem * 9 + w;
      const float4 f = sF[g >> 1];
      const float sx = (g & 1) ? f.z : f.x;
      const float sy = (g & 1) ? f.w : f.y;
      const float qs = fmaf(sx, sx, sy * sy);
      o[w] = fmaf(X02, sx, fmaf(X12, sy, fmaf(-Csl, qs, -Kl)));
    }
    float* base = orow + elem * kW;
    if (elem == 0) {   // base byte-offset 0 (8B-aligned)
      *reinterpret_cast<float2*>(base + 0) = make_float2(o[0], o[1]);
      *reinterpret_cast<float2*>(base + 2) = make_float2(o[2], o[3]);
      *reinterpret_cast<float2*>(base + 4) = make_float2(o[4], o[5]);
      *reinterpret_cast<float2*>(base + 6) = make_float2(o[6], o[7]);
      base[8] = o[8];
    } else {           // base byte-offset 36; base+1 is 8B-aligned
      base[0] = o[0];
      *reinterpret_cast<float2*>(base + 1) = make_float2(o[1], o[2]);
      *reinterpret_cast<float2*>(base + 3) = make_float2(o[3], o[4]);
      *reinterpret_cast<float2*>(base + 5) = make_float2(o[5], o[6]);
      *reinterpret_cast<float2*>(base + 7) = make_float2(o[7], o[8]);
    }
  }
}
}  // namespace

extern "C" void kernel_launch(void* const* d_in, const int* in_sizes, int n_in,
                              void* d_out, int out_size, void* d_ws, size_t ws_size,
                              hipStream_t stream) {
  const float* state     = (const float*)d_in[0];
  const float* constants = (const float*)d_in[1];
  const float* gammas    = (const float*)d_in[2];
  const float* W_body    = (const float*)d_in[3];
  const float* b_body    = (const float*)d_in[4];
  const float* W_head    = (const float*)d_in[5];
  const float* b_head    = (const float*)d_in[6];
  float* out = (float*)d_out;

  const int B = in_sizes[0] / (kW * kL);   // 1048576
  const int pairs = B / 2;                 // 524288 -> 2048 blocks
  hipLaunchKernelGGL(algelogic_pair, dim3(pairs / 256), dim3(256), 0, stream,
                     state, constants, gammas, W_body, b_body, W_head, b_head, out);
}

// Round 18
// 32.187 us; speedup vs baseline: 1.1625x; 1.1625x over previous
//
#include <hip/hip_runtime.h>

namespace {
constexpr int kM = 4, kJ = 2, kI = 3, kL = 2, kW = 9;
constexpr float kInvLn2 = 1.4426950408889634f;

__device__ __forceinline__ float fexp2(float x) { return __builtin_amdgcn_exp2f(x); }

// R16's all-scalar body, single change: __launch_bounds__(256,4) -> 64-VGPR
// cap (hipcc model: 256 regs / min-waves), the configuration that produced
// the best results in R8/R13. Isolates the occupancy-cliff confound.
//
// sdp: 4 records of 20 floats. Record m:
//   [0]An0 [1]An1 [2]B0n0 [3]B0n1 [4]B1n0 [5]B1n1 [6]w0n0 [7]w0n1
//   [8]w1n0 [9]w1n1 [10]C000 [11]C001 [12]C010 [13]C011 [14]C100 [15]C101
//   [16]C110 [17]C111 [18]D0 [19]D1
// msN_j = An_j + sx*(B0n_j + w0n_j*sx) + sy*(B1n_j + w1n_j*sy) = -ms/ln2 <= 0
__global__ __launch_bounds__(256, 4) void algelogic_one(
    const float* __restrict__ state,
    const float* __restrict__ constants,
    const float* __restrict__ gammas,
    const float* __restrict__ W_body,
    const float* __restrict__ b_body,
    const float* __restrict__ W_head,
    const float* __restrict__ b_head,
    float* __restrict__ out) {
  __shared__ float sdp[80];
  const int t = threadIdx.x;
  const int b = blockIdx.x * 256 + t;

  // ---- state loads first (in flight during the fold) ----
  const float2* sr = reinterpret_cast<const float2*>(state) + (size_t)b * kW;
  float s0[kW], s1[kW];
#pragma unroll
  for (int w = 0; w < kW; ++w) {
    const float2 v = sr[w];
    s0[w] = v.x; s1[w] = v.y;
  }

  // ---- param fold: wave0 lanes 0-7 coeffs+C; wave1 lanes 0-3 D ----
  if (t < 8) {
    const int mj = t, m = t >> 1, j = t & 1;
    const float g0 = fminf(fmaxf(gammas[mj * kL + 0], 0.f), 1.f);
    const float g1 = fminf(fmaxf(gammas[mj * kL + 1], 0.f), 1.f);
    const float w0 = 1.f - g0, w1 = 1.f - g1;
    const float c0 = constants[mj * kL + 0], c1 = constants[mj * kL + 1];
    const float gavg = 0.5f * (g0 + g1);
    float* base = sdp + m * 20;
    base[0 + j] = -(w0 * c0 * c0 + w1 * c1 * c1) * kInvLn2;  // An
    base[2 + j] = 2.f * w0 * c0 * kInvLn2;                   // B0n
    base[4 + j] = 2.f * w1 * c1 * kInvLn2;                   // B1n
    base[6 + j] = -w0 * kInvLn2;                             // w0n
    base[8 + j] = -w1 * kInvLn2;                             // w1n
#pragma unroll
    for (int l = 0; l < kL; ++l)
#pragma unroll
      for (int lp = 0; lp < kL; ++lp) {
        float acc = 0.f;
#pragma unroll
        for (int i = 0; i < kI; ++i)
          acc += W_head[(m * kL + l) * kI + i] * W_body[(mj * kI + i) * kL + lp];
        base[10 + (l * 2 + lp) * 2 + j] = gavg * acc;        // C[l][lp], j
      }
  } else if (t >= 64 && t < 68) {
    const int m = t - 64;
#pragma unroll
    for (int l = 0; l < kL; ++l) {
      float d = b_head[m * kL + l];
#pragma unroll
      for (int j = 0; j < kJ; ++j) {
        const int mj = m * kJ + j;
        const float g0 = fminf(fmaxf(gammas[mj * kL + 0], 0.f), 1.f);
        const float g1 = fminf(fmaxf(gammas[mj * kL + 1], 0.f), 1.f);
        const float gavg = 0.5f * (g0 + g1);
        float acc = 0.f;
#pragma unroll
      for (int i = 0; i < kI; ++i)
          acc += W_head[(m * kL + l) * kI + i] * b_body[mj * kI + i];
        d += gavg * acc;
      }
      sdp[m * 20 + 18 + l] = d;
    }
  }
  __syncthreads();

  float Cs = 0.f, X0 = 0.f, X1 = 0.f, K = 0.f;

#pragma unroll 1   // one m live at a time: fits the 64-VGPR cap, no spill
  for (int m = 0; m < kM; ++m) {
    const float4* P4 = reinterpret_cast<const float4*>(sdp + m * 20);
    const float4 f0 = P4[0], f1 = P4[1], f2 = P4[2], f3 = P4[3], f4 = P4[4];
    // f0: An0 An1 B0n0 B0n1 | f1: B1n0 B1n1 w0n0 w0n1 | f2: w1n0 w1n1 C000 C001
    // f3: C010 C011 C100 C101 | f4: C110 C111 D0 D1

    float p0 = 1e-35f, p1 = 1e-35f;        // psum (guard: rcp never sees 0)
    float a0 = 0.f, a1 = 0.f;              // e*sx
    float b0 = 0.f, b1 = 0.f;              // e*sy
    float g0 = 0.f, g1 = 0.f;              // e*msN
#pragma unroll
    for (int w = 0; w < kW; ++w) {
      const float sx = s0[w], sy = s1[w];
      // premise j0
      float u = fmaf(f1.z, sx, f0.z);      // w0n0*sx + B0n0
      float mN0 = fmaf(u, sx, f0.x);       // + An0
      float v = fmaf(f2.x, sy, f1.x);      // w1n0*sy + B1n0
      mN0 = fmaf(v, sy, mN0);              // msN_j0 (<= 0, log2 units)
      const float e0 = fexp2(mN0);
      p0 += e0;
      a0 = fmaf(e0, sx, a0);
      b0 = fmaf(e0, sy, b0);
      g0 = fmaf(e0, mN0, g0);
      // premise j1
      float u1 = fmaf(f1.w, sx, f0.w);     // w0n1*sx + B0n1
      float mN1 = fmaf(u1, sx, f0.y);      // + An1
      float v1 = fmaf(f2.y, sy, f1.y);     // w1n1*sy + B1n1
      mN1 = fmaf(v1, sy, mN1);
      const float e1 = fexp2(mN1);
      p1 += e1;
      a1 = fmaf(e1, sx, a1);
      b1 = fmaf(e1, sy, b1);
      g1 = fmaf(e1, mN1, g1);
    }

    const float i0 = __builtin_amdgcn_rcpf(p0);
    const float i1 = __builtin_amdgcn_rcpf(p1);
    const float bb00 = a0 * i0, bb10 = b0 * i0;   // best_j0: l=0, l=1
    const float bb01 = a1 * i1, bb11 = b1 * i1;   // best_j1
    const float mq2 = fmaf(g0, i0, g1 * i1);      // -mq/ln2 (sum over j)
    const float conf = fexp2(mq2);                // exp(-mq)

    // r_l = D_l + sum_j (C[l][0]_j*bb0_j + C[l][1]_j*bb1_j)
    float r0 = fmaf(f2.z, bb00, f4.z);
    r0 = fmaf(f3.x, bb10, r0);
    r0 = fmaf(f2.w, bb01, r0);
    r0 = fmaf(f3.y, bb11, r0);
    float r1 = fmaf(f3.z, bb00, f4.w);
    r1 = fmaf(f4.x, bb10, r1);
    r1 = fmaf(f3.w, bb01, r1);
    r1 = fmaf(f4.y, bb11, r1);

    Cs += conf;
    X0 = fmaf(conf, r0, X0);
    X1 = fmaf(conf, r1, X1);
    K = fmaf(conf, fmaf(r0, r0, r1 * r1), K);
  }

  const float X02 = 2.f * X0, X12 = 2.f * X1;
  float* orow = out + (size_t)b * kW;
#pragma unroll
  for (int w = 0; w < kW; ++w) {
    const float sx = s0[w], sy = s1[w];
    const float qs = fmaf(sx, sx, sy * sy);
    // out = 2X0*sx + 2X1*sy - Cs*(sx^2+sy^2) - K
    orow[w] = fmaf(X02, sx, fmaf(X12, sy, fmaf(-Cs, qs, -K)));
  }
}
}  // namespace

extern "C" void kernel_launch(void* const* d_in, const int* in_sizes, int n_in,
                              void* d_out, int out_size, void* d_ws, size_t ws_size,
                              hipStream_t stream) {
  const float* state     = (const float*)d_in[0];
  const float* constants = (const float*)d_in[1];
  const float* gammas    = (const float*)d_in[2];
  const float* W_body    = (const float*)d_in[3];
  const float* b_body    = (const float*)d_in[4];
  const float* W_head    = (const float*)d_in[5];
  const float* b_head    = (const float*)d_in[6];
  float* out = (float*)d_out;

  const int B = in_sizes[0] / (kW * kL);   // 1048576
  hipLaunchKernelGGL(algelogic_one, dim3(B / 256), dim3(256), 0, stream,
                     state, constants, gammas, W_body, b_body, W_head, b_head, out);
}

// Round 19
// 31.604 us; speedup vs baseline: 1.1839x; 1.0185x over previous
//
#include <hip/hip_runtime.h>

namespace {
constexpr int kM = 4, kJ = 2, kI = 3, kL = 2, kW = 9;
constexpr float kInvLn2 = 1.4426950408889634f;

typedef float v2f __attribute__((ext_vector_type(2)));

__device__ __forceinline__ float fexp2(float x) { return __builtin_amdgcn_exp2f(x); }

// R13 body (best measured: 30.6us) + persistent-wave grid-stride outer loop:
// 2048 blocks (8/CU, one resident generation), each handles 2 chunks.
// Fold+barrier once per block; chunk 2 runs on warm waves (no teardown/ramp).
//
// sdp layout (80 floats), per m (18 at m*18), j-packed {j0,j1}:
//   [An, B0n, B1n, w0n, w1n, C00, C01, C10, C11]
//   msN = An + sx*(B0n + w0n*sx) + sy*(B1n + w1n*sy)  == -ms/ln2  (<= 0)
// D[m][l] at 72 + m*2 + l.
__global__ __launch_bounds__(256, 4) void algelogic_one(
    const float* __restrict__ state,
    const float* __restrict__ constants,
    const float* __restrict__ gammas,
    const float* __restrict__ W_body,
    const float* __restrict__ b_body,
    const float* __restrict__ W_head,
    const float* __restrict__ b_head,
    float* __restrict__ out) {
  __shared__ float sdp[80];
  const int t = threadIdx.x;

  // ---- param fold: wave0 lanes 0-7 coeffs+C; wave1 lanes 0-3 D ----
  if (t < 8) {
    const int mj = t, m = t >> 1, j = t & 1;
    const float g0 = fminf(fmaxf(gammas[mj * kL + 0], 0.f), 1.f);
    const float g1 = fminf(fmaxf(gammas[mj * kL + 1], 0.f), 1.f);
    const float w0 = 1.f - g0, w1 = 1.f - g1;
    const float c0 = constants[mj * kL + 0], c1 = constants[mj * kL + 1];
    const float gavg = 0.5f * (g0 + g1);
    float* base = sdp + m * 18;
    base[0 * 2 + j] = -(w0 * c0 * c0 + w1 * c1 * c1) * kInvLn2;  // An
    base[1 * 2 + j] = 2.f * w0 * c0 * kInvLn2;                   // B0n
    base[2 * 2 + j] = 2.f * w1 * c1 * kInvLn2;                   // B1n
    base[3 * 2 + j] = -w0 * kInvLn2;                             // w0n
    base[4 * 2 + j] = -w1 * kInvLn2;                             // w1n
#pragma unroll
    for (int l = 0; l < kL; ++l)
#pragma unroll
      for (int lp = 0; lp < kL; ++lp) {
        float acc = 0.f;
#pragma unroll
        for (int i = 0; i < kI; ++i)
          acc += W_head[(m * kL + l) * kI + i] * W_body[(mj * kI + i) * kL + lp];
        base[(5 + l * kL + lp) * 2 + j] = gavg * acc;            // C[l][lp]
      }
  } else if (t >= 64 && t < 68) {
    const int m = t - 64;
#pragma unroll
    for (int l = 0; l < kL; ++l) {
      float d = b_head[m * kL + l];
#pragma unroll
      for (int j = 0; j < kJ; ++j) {
        const int mj = m * kJ + j;
        const float g0 = fminf(fmaxf(gammas[mj * kL + 0], 0.f), 1.f);
        const float g1 = fminf(fmaxf(gammas[mj * kL + 1], 0.f), 1.f);
        const float gavg = 0.5f * (g0 + g1);
        float acc = 0.f;
#pragma unroll
        for (int i = 0; i < kI; ++i)
          acc += W_head[(m * kL + l) * kI + i] * b_body[mj * kI + i];
        d += gavg * acc;
      }
      sdp[72 + m * kL + l] = d;
    }
  }
  __syncthreads();

  // ---- persistent-wave loop: 2 chunks per block ----
#pragma unroll 1
  for (int c = 0; c < 2; ++c) {
    const int b = (c * 2048 + blockIdx.x) * 256 + t;

    const float2* sr = reinterpret_cast<const float2*>(state) + (size_t)b * kW;
    v2f s[kW];
#pragma unroll
    for (int w = 0; w < kW; ++w) {
      const float2 v = sr[w];
      v2f x; x.x = v.x; x.y = v.y;
      s[w] = x;
    }

    float Cs = 0.f, X0 = 0.f, X1 = 0.f, K = 0.f;

#pragma unroll 1   // one m's params live at a time -> VGPR <= 64, no spill
    for (int m = 0; m < kM; ++m) {
      const float* P = sdp + m * 18;
      v2f An  = *reinterpret_cast<const v2f*>(P + 0);
      v2f B0n = *reinterpret_cast<const v2f*>(P + 2);
      v2f B1n = *reinterpret_cast<const v2f*>(P + 4);
      const v2f w0n = *reinterpret_cast<const v2f*>(P + 6);
      const v2f w1n = *reinterpret_cast<const v2f*>(P + 8);
      asm volatile("" : "+v"(An), "+v"(B0n), "+v"(B1n));

      v2f psum = {1e-35f, 1e-35f};   // guard: rcp never sees denormal/0
      v2f pb0 = {0.f, 0.f}, pb1 = {0.f, 0.f}, pmq = {0.f, 0.f};
#pragma unroll
      for (int w = 0; w < kW; ++w) {
        const float sx = s[w].x, sy = s[w].y;
        v2f t0 = B0n + w0n * sx;
        v2f t1 = B1n + w1n * sy;
        v2f msN = An + t0 * sx;
        msN += t1 * sy;                // == -ms/ln2 (<= 0)
        v2f e; e.x = fexp2(msN.x); e.y = fexp2(msN.y);
        psum += e;
        pb0 += e * sx;
        pb1 += e * sy;
        pmq += e * msN;                // = -Σ e·ms/ln2
      }

      v2f rinv;
      rinv.x = __builtin_amdgcn_rcpf(psum.x);
      rinv.y = __builtin_amdgcn_rcpf(psum.y);
      const v2f bb0 = pb0 * rinv, bb1 = pb1 * rinv;
      const v2f mqv = pmq * rinv;
      const float conf = fexp2(mqv.x + mqv.y);   // exp2(-mq/ln2) = exp(-mq)

      const v2f C00 = *reinterpret_cast<const v2f*>(P + 10);
      const v2f C01 = *reinterpret_cast<const v2f*>(P + 12);
      const v2f C10 = *reinterpret_cast<const v2f*>(P + 14);
      const v2f C11 = *reinterpret_cast<const v2f*>(P + 16);
      v2f u0 = C00 * bb0;
      u0 += C01 * bb1;
      v2f u1 = C10 * bb0;
      u1 += C11 * bb1;
      const float r0 = sdp[72 + m * 2 + 0] + u0.x + u0.y;
      const float r1 = sdp[72 + m * 2 + 1] + u1.x + u1.y;

      Cs += conf;
      X0 = fmaf(conf, r0, X0);
      X1 = fmaf(conf, r1, X1);
      K = fmaf(conf, fmaf(r0, r0, r1 * r1), K);
    }

    const float X02 = 2.f * X0, X12 = 2.f * X1;
    float* orow = out + (size_t)b * kW;
#pragma unroll
    for (int w = 0; w < kW; ++w) {
      const float sx = s[w].x, sy = s[w].y;
      const float qs = fmaf(sx, sx, sy * sy);
      // out = 2X0*sx + 2X1*sy - Cs*(sx^2+sy^2) - K
      orow[w] = fmaf(X02, sx, fmaf(X12, sy, fmaf(-Cs, qs, -K)));
    }
  }
}
}  // namespace

extern "C" void kernel_launch(void* const* d_in, const int* in_sizes, int n_in,
                              void* d_out, int out_size, void* d_ws, size_t ws_size,
                              hipStream_t stream) {
  const float* state     = (const float*)d_in[0];
  const float* constants = (const float*)d_in[1];
  const float* gammas    = (const float*)d_in[2];
  const float* W_body    = (const float*)d_in[3];
  const float* b_body    = (const float*)d_in[4];
  const float* W_head    = (const float*)d_in[5];
  const float* b_head    = (const float*)d_in[6];
  float* out = (float*)d_out;

  // B = 1048576 elements; 2048 blocks x 256 threads x 2 chunks (grid-stride)
  hipLaunchKernelGGL(algelogic_one, dim3(2048), dim3(256), 0, stream,
                     state, constants, gammas, W_body, b_body, W_head, b_head, out);
}

// Round 20
// 30.602 us; speedup vs baseline: 1.2227x; 1.0327x over previous
//
#include <hip/hip_runtime.h>

namespace {
constexpr int kM = 4, kJ = 2, kI = 3, kL = 2, kW = 9;
constexpr float kInvLn2 = 1.4426950408889634f;

typedef float v2f __attribute__((ext_vector_type(2)));

__device__ __forceinline__ float fexp2(float x) { return __builtin_amdgcn_exp2f(x); }

// FINAL: exact reversion to the round-13 kernel — best measured (30.6 us).
// Fused single dispatch; in-block param fold on two short parallel chains;
// j-packed v2f body, expanded-Horner negated/log2-scaled match score;
// m-loop kept at unroll 1 (beats full unroll: R10 32.1 vs R13 30.6);
// __launch_bounds__(256,4) = 64-VGPR cap, spill-free.
//
// sdp layout (80 floats), per m (18 floats at m*18), j-packed {j0,j1}:
//   [An, B0n, B1n, w0n, w1n, C00, C01, C10, C11]
//   msN = An + sx*(B0n + w0n*sx) + sy*(B1n + w1n*sy)  == -ms/ln2  (<= 0)
// D[m][l] at 72 + m*2 + l.
__global__ __launch_bounds__(256, 4) void algelogic_one(
    const float* __restrict__ state,
    const float* __restrict__ constants,
    const float* __restrict__ gammas,
    const float* __restrict__ W_body,
    const float* __restrict__ b_body,
    const float* __restrict__ W_head,
    const float* __restrict__ b_head,
    float* __restrict__ out) {
  __shared__ float sdp[80];
  const int t = threadIdx.x;
  const int b = blockIdx.x * 256 + t;

  // ---- state loads issued first (in flight during the fold) ----
  const float2* sr = reinterpret_cast<const float2*>(state) + (size_t)b * kW;
  v2f s[kW];
#pragma unroll
  for (int w = 0; w < kW; ++w) {
    const float2 v = sr[w];
    v2f x; x.x = v.x; x.y = v.y;
    s[w] = x;
  }

  // ---- param fold: wave0 lanes 0-7 coeffs+C; wave1 lanes 0-3 D ----
  if (t < 8) {
    const int mj = t, m = t >> 1, j = t & 1;
    const float g0 = fminf(fmaxf(gammas[mj * kL + 0], 0.f), 1.f);
    const float g1 = fminf(fmaxf(gammas[mj * kL + 1], 0.f), 1.f);
    const float w0 = 1.f - g0, w1 = 1.f - g1;
    const float c0 = constants[mj * kL + 0], c1 = constants[mj * kL + 1];
    const float gavg = 0.5f * (g0 + g1);
    float* base = sdp + m * 18;
    base[0 * 2 + j] = -(w0 * c0 * c0 + w1 * c1 * c1) * kInvLn2;  // An
    base[1 * 2 + j] = 2.f * w0 * c0 * kInvLn2;                   // B0n
    base[2 * 2 + j] = 2.f * w1 * c1 * kInvLn2;                   // B1n
    base[3 * 2 + j] = -w0 * kInvLn2;                             // w0n
    base[4 * 2 + j] = -w1 * kInvLn2;                             // w1n
#pragma unroll
    for (int l = 0; l < kL; ++l)
#pragma unroll
      for (int lp = 0; lp < kL; ++lp) {
        float acc = 0.f;
#pragma unroll
        for (int i = 0; i < kI; ++i)
          acc += W_head[(m * kL + l) * kI + i] * W_body[(mj * kI + i) * kL + lp];
        base[(5 + l * kL + lp) * 2 + j] = gavg * acc;            // C[l][lp]
      }
  } else if (t >= 64 && t < 68) {
    const int m = t - 64;
#pragma unroll
    for (int l = 0; l < kL; ++l) {
      float d = b_head[m * kL + l];
#pragma unroll
      for (int j = 0; j < kJ; ++j) {
        const int mj = m * kJ + j;
        const float g0 = fminf(fmaxf(gammas[mj * kL + 0], 0.f), 1.f);
        const float g1 = fminf(fmaxf(gammas[mj * kL + 1], 0.f), 1.f);
        const float gavg = 0.5f * (g0 + g1);
        float acc = 0.f;
#pragma unroll
        for (int i = 0; i < kI; ++i)
          acc += W_head[(m * kL + l) * kI + i] * b_body[mj * kI + i];
        d += gavg * acc;
      }
      sdp[72 + m * kL + l] = d;
    }
  }
  __syncthreads();

  float Cs = 0.f, X0 = 0.f, X1 = 0.f, K = 0.f;

#pragma unroll 1   // one m's params live at a time (VGPR <= 64, no spill)
  for (int m = 0; m < kM; ++m) {
    const float* P = sdp + m * 18;
    v2f An  = *reinterpret_cast<const v2f*>(P + 0);
    v2f B0n = *reinterpret_cast<const v2f*>(P + 2);
    v2f B1n = *reinterpret_cast<const v2f*>(P + 4);
    const v2f w0n = *reinterpret_cast<const v2f*>(P + 6);
    const v2f w1n = *reinterpret_cast<const v2f*>(P + 8);
    // Keep addends in VGPRs so pk-capable ops see at most one scalar source.
    asm volatile("" : "+v"(An), "+v"(B0n), "+v"(B1n));

    v2f psum = {1e-35f, 1e-35f};   // guard: rcp never sees denormal/0
    v2f pb0 = {0.f, 0.f}, pb1 = {0.f, 0.f}, pmq = {0.f, 0.f};
#pragma unroll
    for (int w = 0; w < kW; ++w) {
      const float sx = s[w].x, sy = s[w].y;
      v2f t0 = B0n + w0n * sx;
      v2f t1 = B1n + w1n * sy;
      v2f msN = An + t0 * sx;
      msN += t1 * sy;                // == -ms/ln2 (<= 0)
      v2f e; e.x = fexp2(msN.x); e.y = fexp2(msN.y);
      psum += e;
      pb0 += e * sx;
      pb1 += e * sy;
      pmq += e * msN;                // = -Σ e·ms/ln2
    }

    v2f rinv;
    rinv.x = __builtin_amdgcn_rcpf(psum.x);
    rinv.y = __builtin_amdgcn_rcpf(psum.y);
    const v2f bb0 = pb0 * rinv, bb1 = pb1 * rinv;
    const v2f mqv = pmq * rinv;
    const float conf = fexp2(mqv.x + mqv.y);   // exp2(-mq/ln2) = exp(-mq)

    const v2f C00 = *reinterpret_cast<const v2f*>(P + 10);
    const v2f C01 = *reinterpret_cast<const v2f*>(P + 12);
    const v2f C10 = *reinterpret_cast<const v2f*>(P + 14);
    const v2f C11 = *reinterpret_cast<const v2f*>(P + 16);
    v2f u0 = C00 * bb0;
    u0 += C01 * bb1;
    v2f u1 = C10 * bb0;
    u1 += C11 * bb1;
    const float r0 = sdp[72 + m * 2 + 0] + u0.x + u0.y;
    const float r1 = sdp[72 + m * 2 + 1] + u1.x + u1.y;

    Cs += conf;
    X0 = fmaf(conf, r0, X0);
    X1 = fmaf(conf, r1, X1);
    K = fmaf(conf, fmaf(r0, r0, r1 * r1), K);
  }

  const float X02 = 2.f * X0, X12 = 2.f * X1;
  float* orow = out + (size_t)b * kW;
#pragma unroll
  for (int w = 0; w < kW; ++w) {
    const float sx = s[w].x, sy = s[w].y;
    const float qs = fmaf(sx, sx, sy * sy);
    // out = 2X0*sx + 2X1*sy - Cs*(sx^2+sy^2) - K
    orow[w] = fmaf(X02, sx, fmaf(X12, sy, fmaf(-Cs, qs, -K)));
  }
}
}  // namespace

extern "C" void kernel_launch(void* const* d_in, const int* in_sizes, int n_in,
                              void* d_out, int out_size, void* d_ws, size_t ws_size,
                              hipStream_t stream) {
  const float* state     = (const float*)d_in[0];
  const float* constants = (const float*)d_in[1];
  const float* gammas    = (const float*)d_in[2];
  const float* W_body    = (const float*)d_in[3];
  const float* b_body    = (const float*)d_in[4];
  const float* W_head    = (const float*)d_in[5];
  const float* b_head    = (const float*)d_in[6];
  float* out = (float*)d_out;

  const int B = in_sizes[0] / (kW * kL);   // 1048576
  hipLaunchKernelGGL(algelogic_one, dim3(B / 256), dim3(256), 0, stream,
                     state, constants, gammas, W_body, b_body, W_head, b_head, out);
}